// Round 1
// baseline (506.316 us; speedup 1.0000x reference)
//
#include <hip/hip_runtime.h>
#include <math.h>

#define N_ROWS 131072   // 32*64*64
#define D 64
#define K 512
#define BLK 256
#define GRID (N_ROWS / BLK)   // 512

// d_out layout (floats):
//   [0]                     loss
//   [1 .. 8388608]          quantized_st, NCHW [32,64,64,64]
//   [8388609]               perplexity
//   [8388610 .. +67108863]  encodings [131072, 512]
//
// d_ws layout (bytes):
//   [0, 2048)      unsigned int counts[512]   (memset to 0 each launch)
//   [2048, 4096)   float e2[512]
//   [4096, 8192)   double loss_partial[512]

__global__ __launch_bounds__(256) void vq_e2_kernel(
    const float* __restrict__ emb, float* __restrict__ e2)
{
    int k = blockIdx.x * blockDim.x + threadIdx.x;
    if (k < K) {
        const float* e = emb + k * D;
        float s = 0.f;
        #pragma unroll
        for (int d = 0; d < D; ++d) s = fmaf(e[d], e[d], s);
        e2[k] = s;
    }
}

__global__ __launch_bounds__(256) void vq_main_kernel(
    const float* __restrict__ in,     // [32,64,64,64] NCHW
    const float* __restrict__ emb,    // [512,64]
    const float* __restrict__ e2,     // [512]
    unsigned int* __restrict__ counts,
    double* __restrict__ lossp,       // [GRID]
    float* __restrict__ quant_out,    // NCHW
    float* __restrict__ enc_out)      // [N_ROWS, 512]
{
    __shared__ int s_idx[BLK];
    __shared__ double s_red[BLK];
    __shared__ unsigned int s_hist[K];

    const int tid = threadIdx.x;
    const int n = blockIdx.x * BLK + tid;      // row index in [B,H,W] order
    const int b = n >> 12;                     // n / 4096
    const int hw = n & 4095;                   // h*64 + w
    const float* xin = in + (size_t)b * 262144 + hw;

    // zero LDS histogram
    for (int k = tid; k < K; k += BLK) s_hist[k] = 0;
    __syncthreads();

    // load x row (coalesced across lanes for each d)
    float x[D];
    #pragma unroll
    for (int d = 0; d < D; ++d) x[d] = xin[d * 4096];

    // argmin over codes: score = ||e||^2 - 2 x.e  (x const per row, dropped)
    float s1 = INFINITY, s2 = INFINITY;
    int i1 = 0, i2 = 0;
    for (int k = 0; k < K; ++k) {
        const float* e = emb + k * D;          // wave-uniform address -> s_load
        float a0 = 0.f, a1 = 0.f, a2 = 0.f, a3 = 0.f;
        #pragma unroll
        for (int d = 0; d < D; d += 4) {
            a0 = fmaf(x[d + 0], e[d + 0], a0);
            a1 = fmaf(x[d + 1], e[d + 1], a1);
            a2 = fmaf(x[d + 2], e[d + 2], a2);
            a3 = fmaf(x[d + 3], e[d + 3], a3);
        }
        float s = e2[k] - 2.f * ((a0 + a1) + (a2 + a3));
        if (s < s1) { s2 = s1; i2 = i1; s1 = s; i1 = k; }
        else if (s < s2) { s2 = s; i2 = k; }
    }

    // fp64 refinement when top-2 nearly tie (makes argmin fp64-exact)
    if (s2 - s1 < 4e-3f) {
        const float* eA = emb + i1 * D;
        const float* eB = emb + i2 * D;
        double dA = 0.0, dB = 0.0;
        for (int d = 0; d < D; ++d) {
            double t = (double)x[d] - (double)eA[d]; dA = fma(t, t, dA);
            double u = (double)x[d] - (double)eB[d]; dB = fma(u, u, dB);
        }
        if (dB < dA || (dB == dA && i2 < i1)) i1 = i2;
    }

    s_idx[tid] = i1;
    atomicAdd(&s_hist[i1], 1u);

    // quantized write (NCHW, coalesced across lanes per d) + loss partial
    const float* eq = emb + i1 * D;
    float* qout = quant_out + (size_t)b * 262144 + hw;
    float lsum = 0.f;
    #pragma unroll 8
    for (int d = 0; d < D; ++d) {
        float q = eq[d];
        float diff = q - x[d];
        lsum = fmaf(diff, diff, lsum);
        qout[d * 4096] = q;
    }

    // block loss reduction (double)
    s_red[tid] = (double)lsum;
    __syncthreads();
    for (int s = BLK / 2; s > 0; s >>= 1) {
        if (tid < s) s_red[tid] += s_red[tid + s];
        __syncthreads();
    }
    if (tid == 0) lossp[blockIdx.x] = s_red[0];

    // flush histogram to global (int atomics: deterministic)
    for (int k = tid; k < K; k += BLK) {
        unsigned int c = s_hist[k];
        if (c) atomicAdd(&counts[k], c);
    }

    // cooperative coalesced one-hot writes: 256 rows x 512 floats
    float* enc = enc_out + (size_t)blockIdx.x * (size_t)(BLK * K);
    for (int r = 0; r < BLK; ++r) {
        int ir = s_idx[r];
        float2 v;
        v.x = (2 * tid     == ir) ? 1.f : 0.f;
        v.y = (2 * tid + 1 == ir) ? 1.f : 0.f;
        *reinterpret_cast<float2*>(enc + (size_t)r * K + 2 * tid) = v;
    }
}

__global__ __launch_bounds__(512) void vq_final_kernel(
    const unsigned int* __restrict__ counts,
    const double* __restrict__ lossp,
    float* __restrict__ out_loss,
    float* __restrict__ out_perp)
{
    __shared__ double sl[512];
    __shared__ double sp[512];
    int t = threadIdx.x;
    double p = (double)counts[t] / (double)N_ROWS;
    sp[t] = p * log(p + 1e-10);
    sl[t] = lossp[t];
    __syncthreads();
    for (int s = 256; s > 0; s >>= 1) {
        if (t < s) { sl[t] += sl[t + s]; sp[t] += sp[t + s]; }
        __syncthreads();
    }
    if (t == 0) {
        *out_loss = (float)(0.25 * sl[0] / 8388608.0);
        *out_perp = (float)exp(-sp[0]);
    }
}

extern "C" void kernel_launch(void* const* d_in, const int* in_sizes, int n_in,
                              void* d_out, int out_size, void* d_ws, size_t ws_size,
                              hipStream_t stream) {
    const float* in  = (const float*)d_in[0];
    const float* emb = (const float*)d_in[1];
    float* out = (float*)d_out;

    unsigned int* counts = (unsigned int*)d_ws;
    float* e2   = (float*)((char*)d_ws + 2048);
    double* lossp = (double*)((char*)d_ws + 4096);

    hipMemsetAsync(d_ws, 0, 2048, stream);
    vq_e2_kernel<<<2, 256, 0, stream>>>(emb, e2);
    vq_main_kernel<<<GRID, BLK, 0, stream>>>(in, emb, e2, counts, lossp,
                                             out + 1, out + 8388610);
    vq_final_kernel<<<1, 512, 0, stream>>>(counts, lossp, out, out + 8388609);
}